// Round 1
// baseline (273.154 us; speedup 1.0000x reference)
//
#include <hip/hip_runtime.h>

// RegionSelector: (64,3,512,512) fp32 -> per-batch argmax of 3x3 grid-cell-window sums -> int32 coords [64,1,2]
//
// Kernel 1: zero 1024-float cell accumulator in d_ws
// Kernel 2: cell sums. block = (b, c, gy, row-half): 64 rows x 512 cols, float4 loads.
//           Each thread's float4 lies in exactly one gx (32 float4 lanes per 128-float cell).
//           LDS tree-reduce per 32-thread group -> atomicAdd into ws[b*16+gy*4+gx].
// Kernel 3: per-b 3x3 window sums over 4x4 cells, first-max argmax, int32 coords.

#define NB 64
#define NC 3
#define HW 512
#define NCELLS (NB * 16)

__global__ void rs_zero_ws(float* __restrict__ ws) {
    int i = blockIdx.x * blockDim.x + threadIdx.x;
    if (i < NCELLS) ws[i] = 0.0f;
}

__global__ __launch_bounds__(256) void rs_cell_sums(const float* __restrict__ in,
                                                    float* __restrict__ ws) {
    // bid = ((b*3 + c)*4 + gy)*2 + half
    const int bid  = blockIdx.x;
    const int half = bid & 1;
    const int gy   = (bid >> 1) & 3;
    const int bc   = bid >> 3;        // b*3 + c
    const int b    = bc / 3;
    const int tid  = threadIdx.x;
    const int col4 = tid & 127;       // float4 column index within 512-wide row
    const int rowp = tid >> 7;        // 0/1: which row of the 2-row stripe
    const int gx   = col4 >> 5;       // 32 float4 lanes per 128-float grid cell

    // base row of this block's 64-row slab
    const float4* base = (const float4*)(in + (((size_t)bc * HW) + gy * 128 + half * 64) * HW);

    float acc = 0.0f;
    #pragma unroll 8
    for (int i = 0; i < 32; ++i) {
        float4 v = base[(size_t)(i * 2 + rowp) * 128 + col4];
        acc += (v.x + v.y) + (v.z + v.w);
    }

    __shared__ float sdata[256];
    sdata[tid] = acc;
    __syncthreads();
    // reduce within each 32-thread group (group = fixed gx)
    for (int s = 16; s > 0; s >>= 1) {
        if ((tid & 31) < s) sdata[tid] += sdata[tid + s];
        __syncthreads();
    }
    if ((tid & 31) == 0) {
        const int cell = b * 16 + gy * 4 + gx;
        atomicAdd(&ws[cell], sdata[tid]);   // device-scope by default on CDNA
    }
}

__global__ void rs_select(const float* __restrict__ ws, int* __restrict__ out) {
    const int b = threadIdx.x;
    if (b >= NB) return;
    float cell[4][4];
    #pragma unroll
    for (int gy = 0; gy < 4; ++gy)
        #pragma unroll
        for (int gx = 0; gx < 4; ++gx)
            cell[gy][gx] = ws[b * 16 + gy * 4 + gx];

    // 3x3 valid window sums over the 4x4 cell grid -> 2x2, flattened row-major
    float w[4];
    int k = 0;
    #pragma unroll
    for (int r = 0; r < 2; ++r)
        #pragma unroll
        for (int c = 0; c < 2; ++c) {
            float s = 0.0f;
            #pragma unroll
            for (int dy = 0; dy < 3; ++dy)
                #pragma unroll
                for (int dx = 0; dx < 3; ++dx)
                    s += cell[r + dy][c + dx];
            w[k++] = s;
        }

    // first-max argmax (lax.top_k tie-break: lowest index wins)
    int best = 0;
    #pragma unroll
    for (int i = 1; i < 4; ++i)
        if (w[i] > w[best]) best = i;

    out[b * 2 + 0] = best >> 1;   // row = idx // 2
    out[b * 2 + 1] = best & 1;    // col = idx % 2
}

extern "C" void kernel_launch(void* const* d_in, const int* in_sizes, int n_in,
                              void* d_out, int out_size, void* d_ws, size_t ws_size,
                              hipStream_t stream) {
    const float* in = (const float*)d_in[0];
    float* ws = (float*)d_ws;          // needs NCELLS*4 = 4 KB
    int* out = (int*)d_out;            // int32 coords, out_size = 128

    rs_zero_ws<<<(NCELLS + 255) / 256, 256, 0, stream>>>(ws);
    rs_cell_sums<<<NB * NC * 4 * 2, 256, 0, stream>>>(in, ws);
    rs_select<<<1, 64, 0, stream>>>(ws, out);
}